// Round 2
// baseline (491.586 us; speedup 1.0000x reference)
//
#include <hip/hip_runtime.h>
#include <hip/hip_bf16.h>
#include <cstdint>

typedef unsigned int uint32;
typedef unsigned short ushort16;
typedef __attribute__((ext_vector_type(8))) short short8;   // 8 bf16 (4 VGPRs)
typedef __attribute__((ext_vector_type(4))) float f32x4;

// fp32 -> bf16 round-to-nearest-even (finite inputs)
__device__ __forceinline__ ushort16 f2bf(float f) {
    uint32 u = __float_as_uint(f);
    u += 0x7fffu + ((u >> 16) & 1u);
    return (ushort16)(u >> 16);
}
__device__ __forceinline__ uint32 packbf2(float lo, float hi) {
    return (uint32)f2bf(lo) | ((uint32)f2bf(hi) << 16);
}
__device__ __forceinline__ float bf_lo(uint32 u) { return __uint_as_float(u << 16); }
__device__ __forceinline__ float bf_hi(uint32 u) { return __uint_as_float(u & 0xffff0000u); }

// async global->LDS, 16B per lane; LDS dest = wave-uniform base + lane*16
__device__ __forceinline__ void gload_lds16(const void* g, void* l) {
    __builtin_amdgcn_global_load_lds(
        (const __attribute__((address_space(1))) uint32*)g,
        (__attribute__((address_space(3))) uint32*)l, 16, 0, 0);
}

// ---------------- weight convert + transpose: Wt[n][k] = bf16(W[k][n]) ----------------
__global__ __launch_bounds__(256) void convertW_kernel(
    const float* __restrict__ W1, const float* __restrict__ W2,
    const float* __restrict__ Wl, ushort16* __restrict__ Wt)
{
    const float* src = blockIdx.z == 0 ? W1 : (blockIdx.z == 1 ? W2 : Wl);
    ushort16* dst = Wt + (size_t)blockIdx.z * 512 * 512;
    __shared__ ushort16 tile[32][33];
    const int n0 = blockIdx.x * 32, k0 = blockIdx.y * 32;
    const int tx = threadIdx.x & 31, ty = threadIdx.x >> 5;
    #pragma unroll
    for (int j = 0; j < 32; j += 8)
        tile[ty + j][tx] = f2bf(src[(size_t)(k0 + ty + j) * 512 + n0 + tx]);
    __syncthreads();
    #pragma unroll
    for (int j = 0; j < 32; j += 8)
        dst[(size_t)(n0 + ty + j) * 512 + k0 + tx] = tile[tx][ty + j];
}

// ---------------- X fp32 -> bf16 (streaming, HBM-bound) ----------------
__global__ __launch_bounds__(256) void convertX_kernel(
    const float* __restrict__ X, ushort16* __restrict__ Xb, int n8)
{
    const int stride = gridDim.x * 256;
    const float4* X4 = (const float4*)X;
    uint4* O = (uint4*)Xb;
    for (int i = blockIdx.x * 256 + threadIdx.x; i < n8; i += stride) {
        float4 a = X4[2 * i], b = X4[2 * i + 1];
        uint4 o;
        o.x = packbf2(a.x, a.y); o.y = packbf2(a.z, a.w);
        o.z = packbf2(b.x, b.y); o.w = packbf2(b.z, b.w);
        O[i] = o;
    }
}

// ---------------- CSR build ----------------
__global__ __launch_bounds__(256) void zero_kernel(int* __restrict__ p, int n) {
    int i = blockIdx.x * 256 + threadIdx.x;
    if (i < n) p[i] = 0;
}
__global__ __launch_bounds__(256) void hist_kernel(
    const int* __restrict__ rows, int* __restrict__ deg, int E)
{
    int e = blockIdx.x * 256 + threadIdx.x;
    if (e < E) atomicAdd(&deg[rows[e]], 1);
}
__global__ __launch_bounds__(256) void scan_block_kernel(
    const int* __restrict__ deg, int* __restrict__ offs, int* __restrict__ bsum)
{
    __shared__ int s[256];
    const int t = threadIdx.x, i = blockIdx.x * 256 + t;
    int v = deg[i];
    s[t] = v; __syncthreads();
    for (int off = 1; off < 256; off <<= 1) {
        int x = (t >= off) ? s[t - off] : 0;
        __syncthreads();
        s[t] += x;
        __syncthreads();
    }
    offs[i] = s[t] - v;
    if (t == 255) bsum[blockIdx.x] = s[t];
}
__global__ __launch_bounds__(256) void scan_top_kernel(int* __restrict__ bsum)
{
    __shared__ int s[256];
    const int t = threadIdx.x;
    int v = bsum[t];
    s[t] = v; __syncthreads();
    for (int off = 1; off < 256; off <<= 1) {
        int x = (t >= off) ? s[t - off] : 0;
        __syncthreads();
        s[t] += x;
        __syncthreads();
    }
    bsum[t] = s[t] - v;
}
__global__ __launch_bounds__(256) void scan_add_kernel(
    int* __restrict__ offs, const int* __restrict__ bsum)
{
    offs[blockIdx.x * 256 + threadIdx.x] += bsum[blockIdx.x];
}
__global__ __launch_bounds__(256) void fill_kernel(
    const int* __restrict__ rows, const int* __restrict__ cols,
    const float* __restrict__ vals, const int* __restrict__ offs,
    int* __restrict__ cursor, int* __restrict__ ecol, float* __restrict__ ew, int E)
{
    int e = blockIdx.x * 256 + threadIdx.x;
    if (e >= E) return;
    int r = rows[e];
    int p = atomicAdd(&cursor[r], 1);
    int s = offs[r] + p;
    ecol[s] = cols[e];
    ew[s] = vals[e];
}

// ---- CSR gather (bf16 in/out, fp32 accum): D[row]=relu(bias + Σ w*S[col] (+Σw*c[g])) ----
template<int WITHC, int SAVEROOT>
__global__ __launch_bounds__(256) void gather_kernel(
    const ushort16* __restrict__ S, ushort16* __restrict__ D,
    const int* __restrict__ offs, const int* __restrict__ deg,
    const int* __restrict__ ecol, const float* __restrict__ ew,
    const float* __restrict__ bias, const float* __restrict__ cadd,
    const int* __restrict__ root_idx, float* __restrict__ hroot, int nPerGraph)
{
    const int wave = threadIdx.x >> 6, l = threadIdx.x & 63;
    const int row = blockIdx.x * 4 + wave;
    const uint4* S4 = (const uint4*)S;     // 64 x uint4 per row
    float acc[8];
    {
        float4 b0 = ((const float4*)bias)[l * 2];
        float4 b1 = ((const float4*)bias)[l * 2 + 1];
        acc[0] = b0.x; acc[1] = b0.y; acc[2] = b0.z; acc[3] = b0.w;
        acc[4] = b1.x; acc[5] = b1.y; acc[6] = b1.z; acc[7] = b1.w;
    }
    const int start = offs[row], d = deg[row];
    float sw = 0.f;
    for (int j = 0; j < d; j++) {
        int col = ecol[start + j];
        float w = ew[start + j];
        uint4 s = S4[(size_t)col * 64 + l];
        acc[0] = fmaf(w, bf_lo(s.x), acc[0]); acc[1] = fmaf(w, bf_hi(s.x), acc[1]);
        acc[2] = fmaf(w, bf_lo(s.y), acc[2]); acc[3] = fmaf(w, bf_hi(s.y), acc[3]);
        acc[4] = fmaf(w, bf_lo(s.z), acc[4]); acc[5] = fmaf(w, bf_hi(s.z), acc[5]);
        acc[6] = fmaf(w, bf_lo(s.w), acc[6]); acc[7] = fmaf(w, bf_hi(s.w), acc[7]);
        sw += w;
    }
    if (WITHC) {
        const float* c = cadd + (size_t)(row / nPerGraph) * 512 + l * 8;
        #pragma unroll
        for (int i = 0; i < 8; i++) acc[i] = fmaf(sw, c[i], acc[i]);
    }
    if (SAVEROOT) {
        int g = row / nPerGraph;
        if (row == root_idx[g]) {
            float* hr = hroot + (size_t)g * 512 + l * 8;
            #pragma unroll
            for (int i = 0; i < 8; i++) hr[i] = acc[i];   // raw (pre-relu) fp32
        }
    }
    uint4 o;
    o.x = packbf2(fmaxf(acc[0], 0.f), fmaxf(acc[1], 0.f));
    o.y = packbf2(fmaxf(acc[2], 0.f), fmaxf(acc[3], 0.f));
    o.z = packbf2(fmaxf(acc[4], 0.f), fmaxf(acc[5], 0.f));
    o.w = packbf2(fmaxf(acc[6], 0.f), fmaxf(acc[7], 0.f));
    ((uint4*)D)[(size_t)row * 64 + l] = o;
}

// ---------------- bf16 MFMA GEMM: C[M,512] = A[M,512] @ Wt^T ----------------
// Counted-vmcnt pipeline (T3+T4): raw s_barrier, stage depth 2, vmcnt(4) steady state
// (never 0 mid-loop). T2 swizzle: global k-chunk ^= (row>>1)&3 on stage, same XOR on
// ds_read -> 2-way bank access (free). Fully unrolled (K=512 fixed, 16 tiles) so
// buffer indices and wait counts are static. A must be bf16 [M][512].
template<int CMODE>
__global__ __launch_bounds__(256) void gemm_mfma_kernel(
    const ushort16* __restrict__ Ab, const ushort16* __restrict__ Bt,
    void* __restrict__ Cvoid, const float* __restrict__ cadd, int nPerGraph)
{
    __shared__ __align__(16) ushort16 As[2][128 * 32];
    __shared__ __align__(16) ushort16 Bs[2][128 * 32];

    const int t = threadIdx.x;
    const int id = blockIdx.x;
    const int bm = (id >> 5) * 8 + (id & 7);
    const int bn = (id >> 3) & 3;
    const int lane = t & 63, wave = t >> 6;
    const int wm = wave >> 1, wn = wave & 1;
    const int quad = lane >> 4, l16 = lane & 15;
    const int grow = lane >> 2;                         // row within 16-row segment
    const int gkc = (((lane & 3) ^ ((grow >> 1) & 3))) * 8;   // swizzled k-chunk (elems)
    const int swz = (l16 >> 1) & 3;                     // read-side chunk XOR

    const ushort16* Bbase = Bt + (size_t)(bn * 128) * 512;

    f32x4 acc[4][4];
    #pragma unroll
    for (int i = 0; i < 4; i++)
        #pragma unroll
        for (int j = 0; j < 4; j++)
            acc[i][j] = (f32x4){0.f, 0.f, 0.f, 0.f};

    // stage one 128x32 K-tile of A and B into buffer `buf` (4 gload_lds per lane)
    auto stage = [&](int k0, int buf) {
        #pragma unroll
        for (int j = 0; j < 2; j++) {
            int seg = wave * 2 + j;
            gload_lds16(Ab + (size_t)(bm * 128 + seg * 16 + grow) * 512 + k0 + gkc,
                        &As[buf][seg * 512 + lane * 8]);
            gload_lds16(Bbase + (size_t)(seg * 16 + grow) * 512 + k0 + gkc,
                        &Bs[buf][seg * 512 + lane * 8]);
        }
    };

    // prologue: 2 tiles in flight
    stage(0, 0);
    stage(32, 1);

    #pragma unroll
    for (int kt = 0; kt < 16; kt++) {
        const int buf = kt & 1;
        // wait for stage(kt); stage(kt+1)'s 4 loads may stay in flight
        if (kt < 15) { asm volatile("s_waitcnt vmcnt(4)" ::: "memory"); }
        else         { asm volatile("s_waitcnt vmcnt(0)" ::: "memory"); }
        __builtin_amdgcn_sched_barrier(0);
        __builtin_amdgcn_s_barrier();          // all waves: stage(kt) landed
        __builtin_amdgcn_sched_barrier(0);

        short8 af[4], bfr[4];
        #pragma unroll
        for (int mi = 0; mi < 4; mi++)
            af[mi] = *(const short8*)
                &As[buf][(wm * 64 + mi * 16 + l16) * 32 + (quad ^ swz) * 8];
        #pragma unroll
        for (int ni = 0; ni < 4; ni++)
            bfr[ni] = *(const short8*)
                &Bs[buf][(wn * 64 + ni * 16 + l16) * 32 + (quad ^ swz) * 8];

        asm volatile("s_waitcnt lgkmcnt(0)" ::: "memory");
        __builtin_amdgcn_sched_barrier(0);
        __builtin_amdgcn_s_barrier();          // all waves done reading buf -> reusable
        __builtin_amdgcn_sched_barrier(0);

        if (kt + 2 < 16) stage((kt + 2) * 32, buf);   // refill freed buffer
        __builtin_amdgcn_sched_barrier(0);

        __builtin_amdgcn_s_setprio(1);
        #pragma unroll
        for (int mi = 0; mi < 4; mi++)
            #pragma unroll
            for (int ni = 0; ni < 4; ni++)
                acc[mi][ni] = __builtin_amdgcn_mfma_f32_16x16x32_bf16(
                    af[mi], bfr[ni], acc[mi][ni], 0, 0, 0);
        __builtin_amdgcn_s_setprio(0);
    }

    if (CMODE == 0) {
        ushort16* C2 = (ushort16*)Cvoid;
        #pragma unroll
        for (int ni = 0; ni < 4; ni++) {
            const int col = bn * 128 + wn * 64 + ni * 16 + l16;
            #pragma unroll
            for (int mi = 0; mi < 4; mi++) {
                const int row0 = bm * 128 + wm * 64 + mi * 16 + quad * 4;
                #pragma unroll
                for (int r = 0; r < 4; r++)
                    C2[(size_t)(row0 + r) * 512 + col] = f2bf(acc[mi][ni][r]);
            }
        }
    } else {
        float* Cf = (float*)Cvoid;
        const int g = (bm * 128) / nPerGraph;
        #pragma unroll
        for (int ni = 0; ni < 4; ni++) {
            const int col = bn * 128 + wn * 64 + ni * 16 + l16;
            const float cv = cadd[(size_t)g * 512 + col];
            #pragma unroll
            for (int mi = 0; mi < 4; mi++) {
                const int row0 = bm * 128 + wm * 64 + mi * 16 + quad * 4;
                #pragma unroll
                for (int r = 0; r < 4; r++) {
                    float v = acc[mi][ni][r] + cv;
                    v = v > 0.f ? v : 0.01f * v;
                    Cf[(size_t)(row0 + r) * 512 + col] = v;
                }
            }
        }
    }
}

// ---------------- per-graph root vectors (fp32, small) ----------------
__global__ __launch_bounds__(256) void rootvec_kernel(
    const float* __restrict__ X, const float* __restrict__ hroot,
    const int* __restrict__ root_idx,
    const float* __restrict__ W2full, const float* __restrict__ Wlfull,
    const float* __restrict__ bl,
    float* __restrict__ c2, float* __restrict__ c3)
{
    __shared__ float xs[512];
    __shared__ float red[4][64];
    const int g = blockIdx.x, which = blockIdx.y, chunk = blockIdx.z;
    const int t = threadIdx.x;
    const float* src = which ? (hroot + (size_t)g * 512)
                             : (X + (size_t)root_idx[g] * 512);
    const float* W = (which ? Wlfull : W2full) + 512 * 512;

    for (int k = t; k < 512; k += 256) {
        float v = src[k];
        if (which == 0) v = fmaxf(v, 0.f);
        xs[k] = v;
    }
    __syncthreads();

    const int col = chunk * 64 + (t & 63), kg = t >> 6;
    float acc = 0.f;
    #pragma unroll 4
    for (int k = kg * 128; k < kg * 128 + 128; k++)
        acc = fmaf(xs[k], W[(size_t)k * 512 + col], acc);
    red[kg][t & 63] = acc;
    __syncthreads();
    if (t < 64) {
        float s = red[0][t] + red[1][t] + red[2][t] + red[3][t];
        int c = chunk * 64 + t;
        if (which) c3[(size_t)g * 512 + c] = s + bl[c];
        else       c2[(size_t)g * 512 + c] = s;
    }
}

extern "C" void kernel_launch(void* const* d_in, const int* in_sizes, int n_in,
                              void* d_out, int out_size, void* d_ws, size_t ws_size,
                              hipStream_t stream)
{
    const float* X        = (const float*)d_in[0];
    const int*   adjs     = (const int*)d_in[1];
    const float* vals     = (const float*)d_in[2];
    const int*   root_idx = (const int*)d_in[3];
    const float* W1       = (const float*)d_in[6];
    const float* b1       = (const float*)d_in[7];
    const float* W2       = (const float*)d_in[8];
    const float* b2       = (const float*)d_in[9];
    const float* Wl       = (const float*)d_in[10];
    const float* bl       = (const float*)d_in[11];
    float* out = (float*)d_out;

    const int M    = in_sizes[0] / 512;   // 65536 nodes total
    const int Etot = in_sizes[2];         // 65536 edges total
    const int Bg   = in_sizes[3];         // 16 graphs
    const int N    = M / Bg;              // 4096 nodes/graph

    // workspace layout
    ushort16* bufS  = (ushort16*)d_ws;                     // support1 / s2 (bf16)
    ushort16* bufH  = bufS + (size_t)M * 512;              // Xb / relu(h1) / relu(agg2)
    ushort16* Wt    = bufH + (size_t)M * 512;              // 3 x 512x512 bf16 [n][k]
    float*    c2    = (float*)(Wt + (size_t)3 * 512 * 512);
    float*    c3    = c2 + (size_t)Bg * 512;
    float*    hroot = c3 + (size_t)Bg * 512;               // raw fp32 h1 root rows
    int*      deg    = (int*)(hroot + (size_t)Bg * 512);
    int*      cursor = deg + M;
    int*      offs   = cursor + M;
    int*      bsum   = offs + M;
    int*      ecol   = bsum + 256;
    float*    ew     = (float*)(ecol + Etot);

    const int* rows = adjs;          // adjs[0] = src (segment target)
    const int* cols = adjs + Etot;   // adjs[1] = dst (gather source)

    const int eBlocks = (Etot + 255) / 256;
    dim3 gemmGrid((M / 128) * 4);    // 1-D, XCD-swizzled inside kernel

    // --- weights -> bf16 transposed; X -> bf16 (into bufH, dead until gather1) ---
    convertW_kernel<<<dim3(16, 16, 3), 256, 0, stream>>>(W1, W2, Wl, Wt);
    convertX_kernel<<<2048, 256, 0, stream>>>(X, bufH, M * 64);

    // --- CSR build ---
    zero_kernel<<<(2 * M + 255) / 256, 256, 0, stream>>>(deg, 2 * M);   // deg + cursor
    hist_kernel<<<eBlocks, 256, 0, stream>>>(rows, deg, Etot);
    scan_block_kernel<<<M / 256, 256, 0, stream>>>(deg, offs, bsum);
    scan_top_kernel<<<1, 256, 0, stream>>>(bsum);
    scan_add_kernel<<<M / 256, 256, 0, stream>>>(offs, bsum);
    fill_kernel<<<eBlocks, 256, 0, stream>>>(rows, cols, vals, offs, cursor, ecol, ew, Etot);

    // --- 1. support1 = Xb @ W1 -> bufS (bf16) ---
    gemm_mfma_kernel<0><<<gemmGrid, 256, 0, stream>>>(bufH, Wt, bufS,
                                                      (const float*)nullptr, N);
    // --- 2. bufH = relu(b1 + gather(w * support1[col])); hroot = raw root rows ---
    gather_kernel<0, 1><<<M / 4, 256, 0, stream>>>(bufS, bufH, offs, deg, ecol, ew, b1,
                                                   (const float*)nullptr, root_idx, hroot, N);
    // --- 3. root vectors: c2 (from X), c3 (from hroot) ---
    rootvec_kernel<<<dim3(Bg, 2, 8), 256, 0, stream>>>(X, hroot, root_idx, W2, Wl, bl, c2, c3);
    // --- 4. s2 = relu(h1) @ W2a -> bufS ---
    gemm_mfma_kernel<0><<<gemmGrid, 256, 0, stream>>>(bufH, Wt + (size_t)512 * 512, bufS,
                                                      (const float*)nullptr, N);
    // --- 5. bufH = relu(b2 + sw*c2[g] + gather(w * s2[col])) ---
    gather_kernel<1, 0><<<M / 4, 256, 0, stream>>>(bufS, bufH, offs, deg, ecol, ew, b2,
                                                   c2, root_idx, (float*)nullptr, N);
    // --- 6. out = leaky(relu(agg2) @ Wla + c3[g]) -> d_out (fp32) ---
    gemm_mfma_kernel<1><<<gemmGrid, 256, 0, stream>>>(bufH, Wt + (size_t)2 * 512 * 512,
                                                      out, c3, N);
}

// Round 4
// 475.630 us; speedup vs baseline: 1.0335x; 1.0335x over previous
//
#include <hip/hip_runtime.h>
#include <hip/hip_bf16.h>
#include <cstdint>

typedef unsigned int uint32;
typedef unsigned short ushort16;
typedef __attribute__((ext_vector_type(8))) short short8;   // 8 bf16 (4 VGPRs)
typedef __attribute__((ext_vector_type(4))) float f32x4;

// fp32 -> bf16 round-to-nearest-even (finite inputs)
__device__ __forceinline__ ushort16 f2bf(float f) {
    uint32 u = __float_as_uint(f);
    u += 0x7fffu + ((u >> 16) & 1u);
    return (ushort16)(u >> 16);
}
__device__ __forceinline__ uint32 packbf2(float lo, float hi) {
    return (uint32)f2bf(lo) | ((uint32)f2bf(hi) << 16);
}
__device__ __forceinline__ float bf_lo(uint32 u) { return __uint_as_float(u << 16); }
__device__ __forceinline__ float bf_hi(uint32 u) { return __uint_as_float(u & 0xffff0000u); }

// async global->LDS, 16B per lane; LDS dest = wave-uniform base + lane*16
__device__ __forceinline__ void gload_lds16(const void* g, void* l) {
    __builtin_amdgcn_global_load_lds(
        (const __attribute__((address_space(1))) uint32*)g,
        (__attribute__((address_space(3))) uint32*)l, 16, 0, 0);
}

// ---------------- weight convert + transpose: Wt[n][k] = bf16(W[k][n]) ----------------
__global__ __launch_bounds__(256) void convertW_kernel(
    const float* __restrict__ W1, const float* __restrict__ W2,
    const float* __restrict__ Wl, ushort16* __restrict__ Wt)
{
    const float* src = blockIdx.z == 0 ? W1 : (blockIdx.z == 1 ? W2 : Wl);
    ushort16* dst = Wt + (size_t)blockIdx.z * 512 * 512;
    __shared__ ushort16 tile[32][33];
    const int n0 = blockIdx.x * 32, k0 = blockIdx.y * 32;
    const int tx = threadIdx.x & 31, ty = threadIdx.x >> 5;
    #pragma unroll
    for (int j = 0; j < 32; j += 8)
        tile[ty + j][tx] = f2bf(src[(size_t)(k0 + ty + j) * 512 + n0 + tx]);
    __syncthreads();
    #pragma unroll
    for (int j = 0; j < 32; j += 8)
        dst[(size_t)(n0 + ty + j) * 512 + k0 + tx] = tile[tx][ty + j];
}

// ---------------- CSR build ----------------
__global__ __launch_bounds__(256) void zero_kernel(int* __restrict__ p, int n) {
    int i = blockIdx.x * 256 + threadIdx.x;
    if (i < n) p[i] = 0;
}
__global__ __launch_bounds__(256) void hist_kernel(
    const int* __restrict__ rows, int* __restrict__ deg, int E)
{
    int e = blockIdx.x * 256 + threadIdx.x;
    if (e < E) atomicAdd(&deg[rows[e]], 1);
}
__global__ __launch_bounds__(256) void scan_block_kernel(
    const int* __restrict__ deg, int* __restrict__ offs, int* __restrict__ bsum)
{
    __shared__ int s[256];
    const int t = threadIdx.x, i = blockIdx.x * 256 + t;
    int v = deg[i];
    s[t] = v; __syncthreads();
    for (int off = 1; off < 256; off <<= 1) {
        int x = (t >= off) ? s[t - off] : 0;
        __syncthreads();
        s[t] += x;
        __syncthreads();
    }
    offs[i] = s[t] - v;
    if (t == 255) bsum[blockIdx.x] = s[t];
}
__global__ __launch_bounds__(256) void scan_top_kernel(int* __restrict__ bsum)
{
    __shared__ int s[256];
    const int t = threadIdx.x;
    int v = bsum[t];
    s[t] = v; __syncthreads();
    for (int off = 1; off < 256; off <<= 1) {
        int x = (t >= off) ? s[t - off] : 0;
        __syncthreads();
        s[t] += x;
        __syncthreads();
    }
    bsum[t] = s[t] - v;
}
__global__ __launch_bounds__(256) void scan_add_kernel(
    int* __restrict__ offs, const int* __restrict__ bsum)
{
    offs[blockIdx.x * 256 + threadIdx.x] += bsum[blockIdx.x];
}
__global__ __launch_bounds__(256) void fill_kernel(
    const int* __restrict__ rows, const int* __restrict__ cols,
    const float* __restrict__ vals, const int* __restrict__ offs,
    int* __restrict__ cursor, int* __restrict__ ecol, float* __restrict__ ew, int E)
{
    int e = blockIdx.x * 256 + threadIdx.x;
    if (e >= E) return;
    int r = rows[e];
    int p = atomicAdd(&cursor[r], 1);
    int s = offs[r] + p;
    ecol[s] = cols[e];
    ew[s] = vals[e];
}

// ---- CSR gather (bf16 in/out, fp32 accum): D[row]=relu(bias + Σ w*S[col] (+Σw*c[g])) ----
template<int WITHC, int SAVEROOT>
__global__ __launch_bounds__(256) void gather_kernel(
    const ushort16* __restrict__ S, ushort16* __restrict__ D,
    const int* __restrict__ offs, const int* __restrict__ deg,
    const int* __restrict__ ecol, const float* __restrict__ ew,
    const float* __restrict__ bias, const float* __restrict__ cadd,
    const int* __restrict__ root_idx, float* __restrict__ hroot, int nPerGraph)
{
    const int wave = threadIdx.x >> 6, l = threadIdx.x & 63;
    const int row = blockIdx.x * 4 + wave;
    const uint4* S4 = (const uint4*)S;     // 64 x uint4 per row
    float acc[8];
    {
        float4 b0 = ((const float4*)bias)[l * 2];
        float4 b1 = ((const float4*)bias)[l * 2 + 1];
        acc[0] = b0.x; acc[1] = b0.y; acc[2] = b0.z; acc[3] = b0.w;
        acc[4] = b1.x; acc[5] = b1.y; acc[6] = b1.z; acc[7] = b1.w;
    }
    const int start = offs[row], d = deg[row];
    float sw = 0.f;
    for (int j = 0; j < d; j++) {
        int col = ecol[start + j];
        float w = ew[start + j];
        uint4 s = S4[(size_t)col * 64 + l];
        acc[0] = fmaf(w, bf_lo(s.x), acc[0]); acc[1] = fmaf(w, bf_hi(s.x), acc[1]);
        acc[2] = fmaf(w, bf_lo(s.y), acc[2]); acc[3] = fmaf(w, bf_hi(s.y), acc[3]);
        acc[4] = fmaf(w, bf_lo(s.z), acc[4]); acc[5] = fmaf(w, bf_hi(s.z), acc[5]);
        acc[6] = fmaf(w, bf_lo(s.w), acc[6]); acc[7] = fmaf(w, bf_hi(s.w), acc[7]);
        sw += w;
    }
    if (WITHC) {
        const float* c = cadd + (size_t)(row / nPerGraph) * 512 + l * 8;
        #pragma unroll
        for (int i = 0; i < 8; i++) acc[i] = fmaf(sw, c[i], acc[i]);
    }
    if (SAVEROOT) {
        int g = row / nPerGraph;
        if (row == root_idx[g]) {
            float* hr = hroot + (size_t)g * 512 + l * 8;
            #pragma unroll
            for (int i = 0; i < 8; i++) hr[i] = acc[i];   // raw (pre-relu) fp32
        }
    }
    uint4 o;
    o.x = packbf2(fmaxf(acc[0], 0.f), fmaxf(acc[1], 0.f));
    o.y = packbf2(fmaxf(acc[2], 0.f), fmaxf(acc[3], 0.f));
    o.z = packbf2(fmaxf(acc[4], 0.f), fmaxf(acc[5], 0.f));
    o.w = packbf2(fmaxf(acc[6], 0.f), fmaxf(acc[7], 0.f));
    ((uint4*)D)[(size_t)row * 64 + l] = o;
}

// ---------------- GEMM #1 (fp32 A, register convert, syncthreads) ----------------
// Exact r0-proven structure: single-buffered LDS, __syncthreads per phase, no swizzle.
// C[M,512] = bf16(A[M,512]) @ Wt^T, C bf16.
__global__ __launch_bounds__(256) void gemm_a32_kernel(
    const float* __restrict__ Af, const ushort16* __restrict__ Bt,
    ushort16* __restrict__ C2)
{
    __shared__ __align__(16) ushort16 As[128 * 32];
    __shared__ __align__(16) ushort16 Bs[128 * 32];

    const int t = threadIdx.x;
    const int id = blockIdx.x;
    const int bm = (id >> 5) * 8 + (id & 7);
    const int bn = (id >> 3) & 3;
    const int lane = t & 63, wave = t >> 6;
    const int wm = wave >> 1, wn = wave & 1;
    const int quad = lane >> 4, l16 = lane & 15;
    const int grow = lane >> 2, gkc = (lane & 3) * 8;   // glds: row-in-seg, k-chunk
    const int sr = t >> 1, sh = (t & 1) * 16;           // fp32 staging: row, k-half

    const ushort16* Bbase = Bt + (size_t)(bn * 128) * 512;

    f32x4 acc[4][4];
    #pragma unroll
    for (int i = 0; i < 4; i++)
        #pragma unroll
        for (int j = 0; j < 4; j++)
            acc[i][j] = (f32x4){0.f, 0.f, 0.f, 0.f};

    for (int k0 = 0; k0 < 512; k0 += 32) {
        {
            const float* ap = Af + (size_t)(bm * 128 + sr) * 512 + k0 + sh;
            float4 a0 = *(const float4*)(ap);
            float4 a1 = *(const float4*)(ap + 4);
            float4 a2 = *(const float4*)(ap + 8);
            float4 a3 = *(const float4*)(ap + 12);
            uint4 w0, w1;
            w0.x = packbf2(a0.x, a0.y); w0.y = packbf2(a0.z, a0.w);
            w0.z = packbf2(a1.x, a1.y); w0.w = packbf2(a1.z, a1.w);
            w1.x = packbf2(a2.x, a2.y); w1.y = packbf2(a2.z, a2.w);
            w1.z = packbf2(a3.x, a3.y); w1.w = packbf2(a3.z, a3.w);
            *(uint4*)&As[sr * 32 + sh] = w0;
            *(uint4*)&As[sr * 32 + sh + 8] = w1;
        }
        #pragma unroll
        for (int j = 0; j < 2; j++) {
            int seg = wave * 2 + j;
            gload_lds16(Bbase + (size_t)(seg * 16 + grow) * 512 + k0 + gkc,
                        &Bs[seg * 512 + lane * 8]);
        }
        __syncthreads();

        short8 af[4], bfr[4];
        #pragma unroll
        for (int mi = 0; mi < 4; mi++)
            af[mi] = *(const short8*)&As[(wm * 64 + mi * 16 + l16) * 32 + quad * 8];
        #pragma unroll
        for (int ni = 0; ni < 4; ni++)
            bfr[ni] = *(const short8*)&Bs[(wn * 64 + ni * 16 + l16) * 32 + quad * 8];
        #pragma unroll
        for (int mi = 0; mi < 4; mi++)
            #pragma unroll
            for (int ni = 0; ni < 4; ni++)
                acc[mi][ni] = __builtin_amdgcn_mfma_f32_16x16x32_bf16(
                    af[mi], bfr[ni], acc[mi][ni], 0, 0, 0);
        __syncthreads();
    }

    #pragma unroll
    for (int ni = 0; ni < 4; ni++) {
        const int col = bn * 128 + wn * 64 + ni * 16 + l16;
        #pragma unroll
        for (int mi = 0; mi < 4; mi++) {
            const int row0 = bm * 128 + wm * 64 + mi * 16 + quad * 4;
            #pragma unroll
            for (int r = 0; r < 4; r++)
                C2[(size_t)(row0 + r) * 512 + col] = f2bf(acc[mi][ni][r]);
        }
    }
}

// ---------------- GEMM #4/#6 (bf16 A via glds, counted-vmcnt pipeline) ----------------
// Exact r2-proven structure: raw s_barrier, stage depth 2, vmcnt(4) steady state,
// chunk-XOR swizzle matched on stage+read. Fully unrolled (K=512, 16 tiles).
template<int CMODE>
__global__ __launch_bounds__(256) void gemm_mfma_kernel(
    const ushort16* __restrict__ Ab, const ushort16* __restrict__ Bt,
    void* __restrict__ Cvoid, const float* __restrict__ cadd, int nPerGraph)
{
    __shared__ __align__(16) ushort16 As[2][128 * 32];
    __shared__ __align__(16) ushort16 Bs[2][128 * 32];

    const int t = threadIdx.x;
    const int id = blockIdx.x;
    const int bm = (id >> 5) * 8 + (id & 7);
    const int bn = (id >> 3) & 3;
    const int lane = t & 63, wave = t >> 6;
    const int wm = wave >> 1, wn = wave & 1;
    const int quad = lane >> 4, l16 = lane & 15;
    const int grow = lane >> 2;                         // row within 16-row segment
    const int gkc = (((lane & 3) ^ ((grow >> 1) & 3))) * 8;   // swizzled k-chunk (elems)
    const int swz = (l16 >> 1) & 3;                     // read-side chunk XOR

    const ushort16* Bbase = Bt + (size_t)(bn * 128) * 512;

    f32x4 acc[4][4];
    #pragma unroll
    for (int i = 0; i < 4; i++)
        #pragma unroll
        for (int j = 0; j < 4; j++)
            acc[i][j] = (f32x4){0.f, 0.f, 0.f, 0.f};

    // stage one 128x32 K-tile of A and B into buffer `buf` (4 gload_lds per lane)
    auto stage = [&](int k0, int buf) {
        #pragma unroll
        for (int j = 0; j < 2; j++) {
            int seg = wave * 2 + j;
            gload_lds16(Ab + (size_t)(bm * 128 + seg * 16 + grow) * 512 + k0 + gkc,
                        &As[buf][seg * 512 + lane * 8]);
            gload_lds16(Bbase + (size_t)(seg * 16 + grow) * 512 + k0 + gkc,
                        &Bs[buf][seg * 512 + lane * 8]);
        }
    };

    // prologue: 2 tiles in flight
    stage(0, 0);
    stage(32, 1);

    #pragma unroll
    for (int kt = 0; kt < 16; kt++) {
        const int buf = kt & 1;
        // wait for stage(kt); stage(kt+1)'s 4 loads may stay in flight
        if (kt < 15) { asm volatile("s_waitcnt vmcnt(4)" ::: "memory"); }
        else         { asm volatile("s_waitcnt vmcnt(0)" ::: "memory"); }
        __builtin_amdgcn_sched_barrier(0);
        __builtin_amdgcn_s_barrier();          // all waves: stage(kt) landed
        __builtin_amdgcn_sched_barrier(0);

        short8 af[4], bfr[4];
        #pragma unroll
        for (int mi = 0; mi < 4; mi++)
            af[mi] = *(const short8*)
                &As[buf][(wm * 64 + mi * 16 + l16) * 32 + (quad ^ swz) * 8];
        #pragma unroll
        for (int ni = 0; ni < 4; ni++)
            bfr[ni] = *(const short8*)
                &Bs[buf][(wn * 64 + ni * 16 + l16) * 32 + (quad ^ swz) * 8];

        asm volatile("s_waitcnt lgkmcnt(0)" ::: "memory");
        __builtin_amdgcn_sched_barrier(0);
        __builtin_amdgcn_s_barrier();          // all waves done reading buf -> reusable
        __builtin_amdgcn_sched_barrier(0);

        if (kt + 2 < 16) stage((kt + 2) * 32, buf);   // refill freed buffer
        __builtin_amdgcn_sched_barrier(0);

        __builtin_amdgcn_s_setprio(1);
        #pragma unroll
        for (int mi = 0; mi < 4; mi++)
            #pragma unroll
            for (int ni = 0; ni < 4; ni++)
                acc[mi][ni] = __builtin_amdgcn_mfma_f32_16x16x32_bf16(
                    af[mi], bfr[ni], acc[mi][ni], 0, 0, 0);
        __builtin_amdgcn_s_setprio(0);
    }

    if (CMODE == 0) {
        ushort16* C2 = (ushort16*)Cvoid;
        #pragma unroll
        for (int ni = 0; ni < 4; ni++) {
            const int col = bn * 128 + wn * 64 + ni * 16 + l16;
            #pragma unroll
            for (int mi = 0; mi < 4; mi++) {
                const int row0 = bm * 128 + wm * 64 + mi * 16 + quad * 4;
                #pragma unroll
                for (int r = 0; r < 4; r++)
                    C2[(size_t)(row0 + r) * 512 + col] = f2bf(acc[mi][ni][r]);
            }
        }
    } else {
        float* Cf = (float*)Cvoid;
        const int g = (bm * 128) / nPerGraph;
        #pragma unroll
        for (int ni = 0; ni < 4; ni++) {
            const int col = bn * 128 + wn * 64 + ni * 16 + l16;
            const float cv = cadd[(size_t)g * 512 + col];
            #pragma unroll
            for (int mi = 0; mi < 4; mi++) {
                const int row0 = bm * 128 + wm * 64 + mi * 16 + quad * 4;
                #pragma unroll
                for (int r = 0; r < 4; r++) {
                    float v = acc[mi][ni][r] + cv;
                    v = v > 0.f ? v : 0.01f * v;
                    Cf[(size_t)(row0 + r) * 512 + col] = v;
                }
            }
        }
    }
}

// ---------------- per-graph root vectors (fp32, small) ----------------
__global__ __launch_bounds__(256) void rootvec_kernel(
    const float* __restrict__ X, const float* __restrict__ hroot,
    const int* __restrict__ root_idx,
    const float* __restrict__ W2full, const float* __restrict__ Wlfull,
    const float* __restrict__ bl,
    float* __restrict__ c2, float* __restrict__ c3)
{
    __shared__ float xs[512];
    __shared__ float red[4][64];
    const int g = blockIdx.x, which = blockIdx.y, chunk = blockIdx.z;
    const int t = threadIdx.x;
    const float* src = which ? (hroot + (size_t)g * 512)
                             : (X + (size_t)root_idx[g] * 512);
    const float* W = (which ? Wlfull : W2full) + 512 * 512;

    for (int k = t; k < 512; k += 256) {
        float v = src[k];
        if (which == 0) v = fmaxf(v, 0.f);
        xs[k] = v;
    }
    __syncthreads();

    const int col = chunk * 64 + (t & 63), kg = t >> 6;
    float acc = 0.f;
    #pragma unroll 4
    for (int k = kg * 128; k < kg * 128 + 128; k++)
        acc = fmaf(xs[k], W[(size_t)k * 512 + col], acc);
    red[kg][t & 63] = acc;
    __syncthreads();
    if (t < 64) {
        float s = red[0][t] + red[1][t] + red[2][t] + red[3][t];
        int c = chunk * 64 + t;
        if (which) c3[(size_t)g * 512 + c] = s + bl[c];
        else       c2[(size_t)g * 512 + c] = s;
    }
}

extern "C" void kernel_launch(void* const* d_in, const int* in_sizes, int n_in,
                              void* d_out, int out_size, void* d_ws, size_t ws_size,
                              hipStream_t stream)
{
    const float* X        = (const float*)d_in[0];
    const int*   adjs     = (const int*)d_in[1];
    const float* vals     = (const float*)d_in[2];
    const int*   root_idx = (const int*)d_in[3];
    const float* W1       = (const float*)d_in[6];
    const float* b1       = (const float*)d_in[7];
    const float* W2       = (const float*)d_in[8];
    const float* b2       = (const float*)d_in[9];
    const float* Wl       = (const float*)d_in[10];
    const float* bl       = (const float*)d_in[11];
    float* out = (float*)d_out;

    const int M    = in_sizes[0] / 512;   // 65536 nodes total
    const int Etot = in_sizes[2];         // 65536 edges total
    const int Bg   = in_sizes[3];         // 16 graphs
    const int N    = M / Bg;              // 4096 nodes/graph

    // workspace layout
    ushort16* bufS  = (ushort16*)d_ws;                     // support1 / s2 (bf16)
    ushort16* bufH  = bufS + (size_t)M * 512;              // relu(h1) / relu(agg2) (bf16)
    ushort16* Wt    = bufH + (size_t)M * 512;              // 3 x 512x512 bf16 [n][k]
    float*    c2    = (float*)(Wt + (size_t)3 * 512 * 512);
    float*    c3    = c2 + (size_t)Bg * 512;
    float*    hroot = c3 + (size_t)Bg * 512;               // raw fp32 h1 root rows
    int*      deg    = (int*)(hroot + (size_t)Bg * 512);
    int*      cursor = deg + M;
    int*      offs   = cursor + M;
    int*      bsum   = offs + M;
    int*      ecol   = bsum + 256;
    float*    ew     = (float*)(ecol + Etot);

    const int* rows = adjs;          // adjs[0] = src (segment target)
    const int* cols = adjs + Etot;   // adjs[1] = dst (gather source)

    const int eBlocks = (Etot + 255) / 256;
    dim3 gemmGrid((M / 128) * 4);    // 1-D, XCD-swizzled inside kernel

    // --- weights -> bf16 transposed ---
    convertW_kernel<<<dim3(16, 16, 3), 256, 0, stream>>>(W1, W2, Wl, Wt);

    // --- CSR build ---
    zero_kernel<<<(2 * M + 255) / 256, 256, 0, stream>>>(deg, 2 * M);   // deg + cursor
    hist_kernel<<<eBlocks, 256, 0, stream>>>(rows, deg, Etot);
    scan_block_kernel<<<M / 256, 256, 0, stream>>>(deg, offs, bsum);
    scan_top_kernel<<<1, 256, 0, stream>>>(bsum);
    scan_add_kernel<<<M / 256, 256, 0, stream>>>(offs, bsum);
    fill_kernel<<<eBlocks, 256, 0, stream>>>(rows, cols, vals, offs, cursor, ecol, ew, Etot);

    // --- 1. support1 = X @ W1 -> bufS (bf16); fp32 A, proven syncthreads kernel ---
    gemm_a32_kernel<<<gemmGrid, 256, 0, stream>>>(X, Wt, bufS);
    // --- 2. bufH = relu(b1 + gather(w * support1[col])); hroot = raw root rows ---
    gather_kernel<0, 1><<<M / 4, 256, 0, stream>>>(bufS, bufH, offs, deg, ecol, ew, b1,
                                                   (const float*)nullptr, root_idx, hroot, N);
    // --- 3. root vectors: c2 (from X), c3 (from hroot) ---
    rootvec_kernel<<<dim3(Bg, 2, 8), 256, 0, stream>>>(X, hroot, root_idx, W2, Wl, bl, c2, c3);
    // --- 4. s2 = relu(h1) @ W2a -> bufS (counted-vmcnt pipeline) ---
    gemm_mfma_kernel<0><<<gemmGrid, 256, 0, stream>>>(bufH, Wt + (size_t)512 * 512, bufS,
                                                      (const float*)nullptr, N);
    // --- 5. bufH = relu(b2 + sw*c2[g] + gather(w * s2[col])) ---
    gather_kernel<1, 0><<<M / 4, 256, 0, stream>>>(bufS, bufH, offs, deg, ecol, ew, b2,
                                                   c2, root_idx, (float*)nullptr, N);
    // --- 6. out = leaky(relu(agg2) @ Wla + c3[g]) -> d_out (fp32) ---
    gemm_mfma_kernel<1><<<gemmGrid, 256, 0, stream>>>(bufH, Wt + (size_t)2 * 512 * 512,
                                                      out, c3, N);
}

// Round 5
// 472.798 us; speedup vs baseline: 1.0397x; 1.0060x over previous
//
#include <hip/hip_runtime.h>
#include <hip/hip_bf16.h>
#include <cstdint>

typedef unsigned int uint32;
typedef unsigned short ushort16;
typedef __attribute__((ext_vector_type(8))) short short8;   // 8 bf16 (4 VGPRs)
typedef __attribute__((ext_vector_type(4))) float f32x4;

// fp32 -> bf16 round-to-nearest-even (finite inputs)
__device__ __forceinline__ ushort16 f2bf(float f) {
    uint32 u = __float_as_uint(f);
    u += 0x7fffu + ((u >> 16) & 1u);
    return (ushort16)(u >> 16);
}
__device__ __forceinline__ uint32 packbf2(float lo, float hi) {
    return (uint32)f2bf(lo) | ((uint32)f2bf(hi) << 16);
}
__device__ __forceinline__ float bf_lo(uint32 u) { return __uint_as_float(u << 16); }
__device__ __forceinline__ float bf_hi(uint32 u) { return __uint_as_float(u & 0xffff0000u); }

// async global->LDS, 16B per lane; LDS dest = wave-uniform base + lane*16
__device__ __forceinline__ void gload_lds16(const void* g, void* l) {
    __builtin_amdgcn_global_load_lds(
        (const __attribute__((address_space(1))) uint32*)g,
        (__attribute__((address_space(3))) uint32*)l, 16, 0, 0);
}

// ---------------- weight convert + transpose: Wt[n][k] = bf16(W[k][n]) ----------------
__global__ __launch_bounds__(256) void convertW_kernel(
    const float* __restrict__ W1, const float* __restrict__ W2,
    const float* __restrict__ Wl, ushort16* __restrict__ Wt)
{
    const float* src = blockIdx.z == 0 ? W1 : (blockIdx.z == 1 ? W2 : Wl);
    ushort16* dst = Wt + (size_t)blockIdx.z * 512 * 512;
    __shared__ ushort16 tile[32][33];
    const int n0 = blockIdx.x * 32, k0 = blockIdx.y * 32;
    const int tx = threadIdx.x & 31, ty = threadIdx.x >> 5;
    #pragma unroll
    for (int j = 0; j < 32; j += 8)
        tile[ty + j][tx] = f2bf(src[(size_t)(k0 + ty + j) * 512 + n0 + tx]);
    __syncthreads();
    #pragma unroll
    for (int j = 0; j < 32; j += 8)
        dst[(size_t)(n0 + ty + j) * 512 + k0 + tx] = tile[tx][ty + j];
}

// ---------------- CSR build ----------------
__global__ __launch_bounds__(256) void zero_kernel(int* __restrict__ p, int n) {
    int i = blockIdx.x * 256 + threadIdx.x;
    if (i < n) p[i] = 0;
}
__global__ __launch_bounds__(256) void hist_kernel(
    const int* __restrict__ rows, int* __restrict__ deg, int E)
{
    int e = blockIdx.x * 256 + threadIdx.x;
    if (e < E) atomicAdd(&deg[rows[e]], 1);
}
__global__ __launch_bounds__(256) void scan_block_kernel(
    const int* __restrict__ deg, int* __restrict__ offs, int* __restrict__ bsum)
{
    __shared__ int s[256];
    const int t = threadIdx.x, i = blockIdx.x * 256 + t;
    int v = deg[i];
    s[t] = v; __syncthreads();
    for (int off = 1; off < 256; off <<= 1) {
        int x = (t >= off) ? s[t - off] : 0;
        __syncthreads();
        s[t] += x;
        __syncthreads();
    }
    offs[i] = s[t] - v;
    if (t == 255) bsum[blockIdx.x] = s[t];
}
__global__ __launch_bounds__(256) void scan_top_kernel(int* __restrict__ bsum)
{
    __shared__ int s[256];
    const int t = threadIdx.x;
    int v = bsum[t];
    s[t] = v; __syncthreads();
    for (int off = 1; off < 256; off <<= 1) {
        int x = (t >= off) ? s[t - off] : 0;
        __syncthreads();
        s[t] += x;
        __syncthreads();
    }
    bsum[t] = s[t] - v;
}
__global__ __launch_bounds__(256) void scan_add_kernel(
    int* __restrict__ offs, const int* __restrict__ bsum)
{
    offs[blockIdx.x * 256 + threadIdx.x] += bsum[blockIdx.x];
}
__global__ __launch_bounds__(256) void fill_kernel(
    const int* __restrict__ rows, const int* __restrict__ cols,
    const float* __restrict__ vals, const int* __restrict__ offs,
    int* __restrict__ cursor, int* __restrict__ ecol, float* __restrict__ ew, int E)
{
    int e = blockIdx.x * 256 + threadIdx.x;
    if (e >= E) return;
    int r = rows[e];
    int p = atomicAdd(&cursor[r], 1);
    int s = offs[r] + p;
    ecol[s] = cols[e];
    ew[s] = vals[e];
}

// ---- CSR gather on fp32 X -> bf16 aggX: D[row] = Σ w * X[col]  (no bias, no relu) ----
// Linearity: Agg(X@W1) == (Agg X)@W1, so layer-1 gathers BEFORE the GEMM.
__global__ __launch_bounds__(256) void gatherX_kernel(
    const float* __restrict__ X, ushort16* __restrict__ D,
    const int* __restrict__ offs, const int* __restrict__ deg,
    const int* __restrict__ ecol, const float* __restrict__ ew)
{
    const int wave = threadIdx.x >> 6, l = threadIdx.x & 63;
    const int row = blockIdx.x * 4 + wave;
    float acc[8];
    #pragma unroll
    for (int i = 0; i < 8; i++) acc[i] = 0.f;
    const int start = offs[row], d = deg[row];
    for (int j = 0; j < d; j++) {
        int col = ecol[start + j];
        float w = ew[start + j];
        const float4* xr = (const float4*)(X + (size_t)col * 512) + l * 2;
        float4 a = xr[0], b = xr[1];
        acc[0] = fmaf(w, a.x, acc[0]); acc[1] = fmaf(w, a.y, acc[1]);
        acc[2] = fmaf(w, a.z, acc[2]); acc[3] = fmaf(w, a.w, acc[3]);
        acc[4] = fmaf(w, b.x, acc[4]); acc[5] = fmaf(w, b.y, acc[5]);
        acc[6] = fmaf(w, b.z, acc[6]); acc[7] = fmaf(w, b.w, acc[7]);
    }
    uint4 o;
    o.x = packbf2(acc[0], acc[1]);
    o.y = packbf2(acc[2], acc[3]);
    o.z = packbf2(acc[4], acc[5]);
    o.w = packbf2(acc[6], acc[7]);
    ((uint4*)D)[(size_t)row * 64 + l] = o;
}

// ---- CSR gather (bf16 in/out, fp32 accum): D[row]=relu(bias + Σ w*S[col] + Σw*c[g]) ----
__global__ __launch_bounds__(256) void gather_kernel(
    const ushort16* __restrict__ S, ushort16* __restrict__ D,
    const int* __restrict__ offs, const int* __restrict__ deg,
    const int* __restrict__ ecol, const float* __restrict__ ew,
    const float* __restrict__ bias, const float* __restrict__ cadd, int nPerGraph)
{
    const int wave = threadIdx.x >> 6, l = threadIdx.x & 63;
    const int row = blockIdx.x * 4 + wave;
    const uint4* S4 = (const uint4*)S;     // 64 x uint4 per row
    float acc[8];
    {
        float4 b0 = ((const float4*)bias)[l * 2];
        float4 b1 = ((const float4*)bias)[l * 2 + 1];
        acc[0] = b0.x; acc[1] = b0.y; acc[2] = b0.z; acc[3] = b0.w;
        acc[4] = b1.x; acc[5] = b1.y; acc[6] = b1.z; acc[7] = b1.w;
    }
    const int start = offs[row], d = deg[row];
    float sw = 0.f;
    for (int j = 0; j < d; j++) {
        int col = ecol[start + j];
        float w = ew[start + j];
        uint4 s = S4[(size_t)col * 64 + l];
        acc[0] = fmaf(w, bf_lo(s.x), acc[0]); acc[1] = fmaf(w, bf_hi(s.x), acc[1]);
        acc[2] = fmaf(w, bf_lo(s.y), acc[2]); acc[3] = fmaf(w, bf_hi(s.y), acc[3]);
        acc[4] = fmaf(w, bf_lo(s.z), acc[4]); acc[5] = fmaf(w, bf_hi(s.z), acc[5]);
        acc[6] = fmaf(w, bf_lo(s.w), acc[6]); acc[7] = fmaf(w, bf_hi(s.w), acc[7]);
        sw += w;
    }
    {
        const float* c = cadd + (size_t)(row / nPerGraph) * 512 + l * 8;
        #pragma unroll
        for (int i = 0; i < 8; i++) acc[i] = fmaf(sw, c[i], acc[i]);
    }
    uint4 o;
    o.x = packbf2(fmaxf(acc[0], 0.f), fmaxf(acc[1], 0.f));
    o.y = packbf2(fmaxf(acc[2], 0.f), fmaxf(acc[3], 0.f));
    o.z = packbf2(fmaxf(acc[4], 0.f), fmaxf(acc[5], 0.f));
    o.w = packbf2(fmaxf(acc[6], 0.f), fmaxf(acc[7], 0.f));
    ((uint4*)D)[(size_t)row * 64 + l] = o;
}

// ---------------- bf16 MFMA GEMM: C[M,512] = A[M,512] @ Wt^T ----------------
// r2/r4-proven counted-vmcnt pipeline: raw s_barrier, stage depth 2, vmcnt(4) steady
// state (never 0 mid-loop), chunk-XOR swizzle matched on stage+read. Fully unrolled
// (K=512, 16 tiles). Epilogues:
// CMODE 0: C bf16 plain.
// CMODE 1: C fp32, += cadd[g] (per-graph vec), leaky_relu.
// CMODE 2: C bf16 = relu(acc + cadd[col] (bias)); root row saved pre-relu fp32 -> hroot.
template<int CMODE>
__global__ __launch_bounds__(256) void gemm_mfma_kernel(
    const ushort16* __restrict__ Ab, const ushort16* __restrict__ Bt,
    void* __restrict__ Cvoid, const float* __restrict__ cadd,
    const int* __restrict__ root_idx, float* __restrict__ hroot, int nPerGraph)
{
    __shared__ __align__(16) ushort16 As[2][128 * 32];
    __shared__ __align__(16) ushort16 Bs[2][128 * 32];

    const int t = threadIdx.x;
    const int id = blockIdx.x;
    const int bm = (id >> 5) * 8 + (id & 7);
    const int bn = (id >> 3) & 3;
    const int lane = t & 63, wave = t >> 6;
    const int wm = wave >> 1, wn = wave & 1;
    const int quad = lane >> 4, l16 = lane & 15;
    const int grow = lane >> 2;                         // row within 16-row segment
    const int gkc = (((lane & 3) ^ ((grow >> 1) & 3))) * 8;   // swizzled k-chunk (elems)
    const int swz = (l16 >> 1) & 3;                     // read-side chunk XOR

    const ushort16* Bbase = Bt + (size_t)(bn * 128) * 512;

    f32x4 acc[4][4];
    #pragma unroll
    for (int i = 0; i < 4; i++)
        #pragma unroll
        for (int j = 0; j < 4; j++)
            acc[i][j] = (f32x4){0.f, 0.f, 0.f, 0.f};

    // stage one 128x32 K-tile of A and B into buffer `buf` (4 gload_lds per lane)
    auto stage = [&](int k0, int buf) {
        #pragma unroll
        for (int j = 0; j < 2; j++) {
            int seg = wave * 2 + j;
            gload_lds16(Ab + (size_t)(bm * 128 + seg * 16 + grow) * 512 + k0 + gkc,
                        &As[buf][seg * 512 + lane * 8]);
            gload_lds16(Bbase + (size_t)(seg * 16 + grow) * 512 + k0 + gkc,
                        &Bs[buf][seg * 512 + lane * 8]);
        }
    };

    // prologue: 2 tiles in flight
    stage(0, 0);
    stage(32, 1);

    #pragma unroll
    for (int kt = 0; kt < 16; kt++) {
        const int buf = kt & 1;
        // wait for stage(kt); stage(kt+1)'s 4 loads may stay in flight
        if (kt < 15) { asm volatile("s_waitcnt vmcnt(4)" ::: "memory"); }
        else         { asm volatile("s_waitcnt vmcnt(0)" ::: "memory"); }
        __builtin_amdgcn_sched_barrier(0);
        __builtin_amdgcn_s_barrier();          // all waves: stage(kt) landed
        __builtin_amdgcn_sched_barrier(0);

        short8 af[4], bfr[4];
        #pragma unroll
        for (int mi = 0; mi < 4; mi++)
            af[mi] = *(const short8*)
                &As[buf][(wm * 64 + mi * 16 + l16) * 32 + (quad ^ swz) * 8];
        #pragma unroll
        for (int ni = 0; ni < 4; ni++)
            bfr[ni] = *(const short8*)
                &Bs[buf][(wn * 64 + ni * 16 + l16) * 32 + (quad ^ swz) * 8];

        asm volatile("s_waitcnt lgkmcnt(0)" ::: "memory");
        __builtin_amdgcn_sched_barrier(0);
        __builtin_amdgcn_s_barrier();          // all waves done reading buf -> reusable
        __builtin_amdgcn_sched_barrier(0);

        if (kt + 2 < 16) stage((kt + 2) * 32, buf);   // refill freed buffer
        __builtin_amdgcn_sched_barrier(0);

        __builtin_amdgcn_s_setprio(1);
        #pragma unroll
        for (int mi = 0; mi < 4; mi++)
            #pragma unroll
            for (int ni = 0; ni < 4; ni++)
                acc[mi][ni] = __builtin_amdgcn_mfma_f32_16x16x32_bf16(
                    af[mi], bfr[ni], acc[mi][ni], 0, 0, 0);
        __builtin_amdgcn_s_setprio(0);
    }

    if (CMODE == 0) {
        ushort16* C2 = (ushort16*)Cvoid;
        #pragma unroll
        for (int ni = 0; ni < 4; ni++) {
            const int col = bn * 128 + wn * 64 + ni * 16 + l16;
            #pragma unroll
            for (int mi = 0; mi < 4; mi++) {
                const int row0 = bm * 128 + wm * 64 + mi * 16 + quad * 4;
                #pragma unroll
                for (int r = 0; r < 4; r++)
                    C2[(size_t)(row0 + r) * 512 + col] = f2bf(acc[mi][ni][r]);
            }
        }
    } else if (CMODE == 1) {
        float* Cf = (float*)Cvoid;
        const int g = (bm * 128) / nPerGraph;
        #pragma unroll
        for (int ni = 0; ni < 4; ni++) {
            const int col = bn * 128 + wn * 64 + ni * 16 + l16;
            const float cv = cadd[(size_t)g * 512 + col];
            #pragma unroll
            for (int mi = 0; mi < 4; mi++) {
                const int row0 = bm * 128 + wm * 64 + mi * 16 + quad * 4;
                #pragma unroll
                for (int r = 0; r < 4; r++) {
                    float v = acc[mi][ni][r] + cv;
                    v = v > 0.f ? v : 0.01f * v;
                    Cf[(size_t)(row0 + r) * 512 + col] = v;
                }
            }
        }
    } else {   // CMODE == 2: h1 epilogue — +bias, relu, root-row fp32 save
        ushort16* C2 = (ushort16*)Cvoid;
        const int g = (bm * 128) / nPerGraph;
        const int root = root_idx[g];
        #pragma unroll
        for (int ni = 0; ni < 4; ni++) {
            const int col = bn * 128 + wn * 64 + ni * 16 + l16;
            const float bv = cadd[col];
            #pragma unroll
            for (int mi = 0; mi < 4; mi++) {
                const int row0 = bm * 128 + wm * 64 + mi * 16 + quad * 4;
                #pragma unroll
                for (int r = 0; r < 4; r++) {
                    float v = acc[mi][ni][r] + bv;
                    if (row0 + r == root)
                        hroot[(size_t)g * 512 + col] = v;   // raw (pre-relu) fp32
                    C2[(size_t)(row0 + r) * 512 + col] = f2bf(fmaxf(v, 0.f));
                }
            }
        }
    }
}

// ---------------- per-graph root vectors (fp32, small) ----------------
__global__ __launch_bounds__(256) void rootvec_kernel(
    const float* __restrict__ X, const float* __restrict__ hroot,
    const int* __restrict__ root_idx,
    const float* __restrict__ W2full, const float* __restrict__ Wlfull,
    const float* __restrict__ bl,
    float* __restrict__ c2, float* __restrict__ c3)
{
    __shared__ float xs[512];
    __shared__ float red[4][64];
    const int g = blockIdx.x, which = blockIdx.y, chunk = blockIdx.z;
    const int t = threadIdx.x;
    const float* src = which ? (hroot + (size_t)g * 512)
                             : (X + (size_t)root_idx[g] * 512);
    const float* W = (which ? Wlfull : W2full) + 512 * 512;

    for (int k = t; k < 512; k += 256) {
        float v = src[k];
        if (which == 0) v = fmaxf(v, 0.f);
        xs[k] = v;
    }
    __syncthreads();

    const int col = chunk * 64 + (t & 63), kg = t >> 6;
    float acc = 0.f;
    #pragma unroll 4
    for (int k = kg * 128; k < kg * 128 + 128; k++)
        acc = fmaf(xs[k], W[(size_t)k * 512 + col], acc);
    red[kg][t & 63] = acc;
    __syncthreads();
    if (t < 64) {
        float s = red[0][t] + red[1][t] + red[2][t] + red[3][t];
        int c = chunk * 64 + t;
        if (which) c3[(size_t)g * 512 + c] = s + bl[c];
        else       c2[(size_t)g * 512 + c] = s;
    }
}

extern "C" void kernel_launch(void* const* d_in, const int* in_sizes, int n_in,
                              void* d_out, int out_size, void* d_ws, size_t ws_size,
                              hipStream_t stream)
{
    const float* X        = (const float*)d_in[0];
    const int*   adjs     = (const int*)d_in[1];
    const float* vals     = (const float*)d_in[2];
    const int*   root_idx = (const int*)d_in[3];
    const float* W1       = (const float*)d_in[6];
    const float* b1       = (const float*)d_in[7];
    const float* W2       = (const float*)d_in[8];
    const float* b2       = (const float*)d_in[9];
    const float* Wl       = (const float*)d_in[10];
    const float* bl       = (const float*)d_in[11];
    float* out = (float*)d_out;

    const int M    = in_sizes[0] / 512;   // 65536 nodes total
    const int Etot = in_sizes[2];         // 65536 edges total
    const int Bg   = in_sizes[3];         // 16 graphs
    const int N    = M / Bg;              // 4096 nodes/graph

    // workspace layout
    ushort16* bufS  = (ushort16*)d_ws;                     // aggX / s2 (bf16)
    ushort16* bufH  = bufS + (size_t)M * 512;              // relu(h1) / relu(agg2) (bf16)
    ushort16* Wt    = bufH + (size_t)M * 512;              // 3 x 512x512 bf16 [n][k]
    float*    c2    = (float*)(Wt + (size_t)3 * 512 * 512);
    float*    c3    = c2 + (size_t)Bg * 512;
    float*    hroot = c3 + (size_t)Bg * 512;               // raw fp32 h1 root rows
    int*      deg    = (int*)(hroot + (size_t)Bg * 512);
    int*      cursor = deg + M;
    int*      offs   = cursor + M;
    int*      bsum   = offs + M;
    int*      ecol   = bsum + 256;
    float*    ew     = (float*)(ecol + Etot);

    const int* rows = adjs;          // adjs[0] = src (segment target)
    const int* cols = adjs + Etot;   // adjs[1] = dst (gather source)

    const int eBlocks = (Etot + 255) / 256;
    dim3 gemmGrid((M / 128) * 4);    // 1-D, XCD-swizzled inside kernel

    // --- weights -> bf16 transposed ---
    convertW_kernel<<<dim3(16, 16, 3), 256, 0, stream>>>(W1, W2, Wl, Wt);

    // --- CSR build ---
    zero_kernel<<<(2 * M + 255) / 256, 256, 0, stream>>>(deg, 2 * M);   // deg + cursor
    hist_kernel<<<eBlocks, 256, 0, stream>>>(rows, deg, Etot);
    scan_block_kernel<<<M / 256, 256, 0, stream>>>(deg, offs, bsum);
    scan_top_kernel<<<1, 256, 0, stream>>>(bsum);
    scan_add_kernel<<<M / 256, 256, 0, stream>>>(offs, bsum);
    fill_kernel<<<eBlocks, 256, 0, stream>>>(rows, cols, vals, offs, cursor, ecol, ew, Etot);

    // --- 1a. aggX = gather(X) -> bufS (bf16). Linearity: Agg(X@W1) == (AggX)@W1 ---
    gatherX_kernel<<<M / 4, 256, 0, stream>>>(X, bufS, offs, deg, ecol, ew);
    // --- 1b. bufH = relu(b1 + aggX @ W1); hroot = raw fp32 root rows (pre-relu) ---
    gemm_mfma_kernel<2><<<gemmGrid, 256, 0, stream>>>(bufS, Wt, bufH, b1,
                                                      root_idx, hroot, N);
    // --- 2. root vectors: c2 (from X), c3 (from hroot) ---
    rootvec_kernel<<<dim3(Bg, 2, 8), 256, 0, stream>>>(X, hroot, root_idx, W2, Wl, bl, c2, c3);
    // --- 3. s2 = relu(h1) @ W2a -> bufS (counted-vmcnt pipeline) ---
    gemm_mfma_kernel<0><<<gemmGrid, 256, 0, stream>>>(bufH, Wt + (size_t)512 * 512, bufS,
                                                      (const float*)nullptr,
                                                      (const int*)nullptr, (float*)nullptr, N);
    // --- 4. bufH = relu(b2 + sw*c2[g] + gather(w * s2[col])) ---
    gather_kernel<<<M / 4, 256, 0, stream>>>(bufS, bufH, offs, deg, ecol, ew, b2, c2, N);
    // --- 5. out = leaky(relu(agg2) @ Wla + c3[g]) -> d_out (fp32) ---
    gemm_mfma_kernel<1><<<gemmGrid, 256, 0, stream>>>(bufH, Wt + (size_t)2 * 512 * 512,
                                                      out, c3,
                                                      (const int*)nullptr, (float*)nullptr, N);
}

// Round 6
// 471.149 us; speedup vs baseline: 1.0434x; 1.0035x over previous
//
#include <hip/hip_runtime.h>
#include <hip/hip_bf16.h>
#include <cstdint>

typedef unsigned int uint32;
typedef unsigned short ushort16;
typedef __attribute__((ext_vector_type(8))) short short8;   // 8 bf16 (4 VGPRs)
typedef __attribute__((ext_vector_type(4))) float f32x4;

// fp32 -> bf16 round-to-nearest-even (finite inputs)
__device__ __forceinline__ ushort16 f2bf(float f) {
    uint32 u = __float_as_uint(f);
    u += 0x7fffu + ((u >> 16) & 1u);
    return (ushort16)(u >> 16);
}
__device__ __forceinline__ uint32 packbf2(float lo, float hi) {
    return (uint32)f2bf(lo) | ((uint32)f2bf(hi) << 16);
}
__device__ __forceinline__ float bf_lo(uint32 u) { return __uint_as_float(u << 16); }
__device__ __forceinline__ float bf_hi(uint32 u) { return __uint_as_float(u & 0xffff0000u); }

// async global->LDS, 16B per lane; LDS dest = wave-uniform base + lane*16
__device__ __forceinline__ void gload_lds16(const void* g, void* l) {
    __builtin_amdgcn_global_load_lds(
        (const __attribute__((address_space(1))) uint32*)g,
        (__attribute__((address_space(3))) uint32*)l, 16, 0, 0);
}

// ---------------- weight convert + transpose: Wt[n][k] = bf16(W[k][n]) ----------------
__global__ __launch_bounds__(256) void convertW_kernel(
    const float* __restrict__ W1, const float* __restrict__ W2,
    const float* __restrict__ Wl, ushort16* __restrict__ Wt)
{
    const float* src = blockIdx.z == 0 ? W1 : (blockIdx.z == 1 ? W2 : Wl);
    ushort16* dst = Wt + (size_t)blockIdx.z * 512 * 512;
    __shared__ ushort16 tile[32][33];
    const int n0 = blockIdx.x * 32, k0 = blockIdx.y * 32;
    const int tx = threadIdx.x & 31, ty = threadIdx.x >> 5;
    #pragma unroll
    for (int j = 0; j < 32; j += 8)
        tile[ty + j][tx] = f2bf(src[(size_t)(k0 + ty + j) * 512 + n0 + tx]);
    __syncthreads();
    #pragma unroll
    for (int j = 0; j < 32; j += 8)
        dst[(size_t)(n0 + ty + j) * 512 + k0 + tx] = tile[tx][ty + j];
}

// ---------------- CSR build ----------------
__global__ __launch_bounds__(256) void zero_kernel(int* __restrict__ p, int n) {
    int i = blockIdx.x * 256 + threadIdx.x;
    if (i < n) p[i] = 0;
}
__global__ __launch_bounds__(256) void hist_kernel(
    const int* __restrict__ rows, int* __restrict__ deg, int E)
{
    int e = blockIdx.x * 256 + threadIdx.x;
    if (e < E) atomicAdd(&deg[rows[e]], 1);
}
__global__ __launch_bounds__(256) void scan_block_kernel(
    const int* __restrict__ deg, int* __restrict__ offs, int* __restrict__ bsum)
{
    __shared__ int s[256];
    const int t = threadIdx.x, i = blockIdx.x * 256 + t;
    int v = deg[i];
    s[t] = v; __syncthreads();
    for (int off = 1; off < 256; off <<= 1) {
        int x = (t >= off) ? s[t - off] : 0;
        __syncthreads();
        s[t] += x;
        __syncthreads();
    }
    offs[i] = s[t] - v;
    if (t == 255) bsum[blockIdx.x] = s[t];
}
__global__ __launch_bounds__(256) void scan_top_kernel(int* __restrict__ bsum)
{
    __shared__ int s[256];
    const int t = threadIdx.x;
    int v = bsum[t];
    s[t] = v; __syncthreads();
    for (int off = 1; off < 256; off <<= 1) {
        int x = (t >= off) ? s[t - off] : 0;
        __syncthreads();
        s[t] += x;
        __syncthreads();
    }
    bsum[t] = s[t] - v;
}
__global__ __launch_bounds__(256) void scan_add_kernel(
    int* __restrict__ offs, const int* __restrict__ bsum)
{
    offs[blockIdx.x * 256 + threadIdx.x] += bsum[blockIdx.x];
}
__global__ __launch_bounds__(256) void fill_kernel(
    const int* __restrict__ rows, const int* __restrict__ cols,
    const float* __restrict__ vals, const int* __restrict__ offs,
    int* __restrict__ cursor, int* __restrict__ ecol, float* __restrict__ ew, int E)
{
    int e = blockIdx.x * 256 + threadIdx.x;
    if (e >= E) return;
    int r = rows[e];
    int p = atomicAdd(&cursor[r], 1);
    int s = offs[r] + p;
    ecol[s] = cols[e];
    ew[s] = vals[e];
}

// ---- CSR gather on fp32 X -> bf16 aggX: D[row] = Σ w * X[col]  (no bias, no relu) ----
// Linearity: Agg(X@W1) == (Agg X)@W1, so layer-1 gathers BEFORE the GEMM.
__global__ __launch_bounds__(256) void gatherX_kernel(
    const float* __restrict__ X, ushort16* __restrict__ D,
    const int* __restrict__ offs, const int* __restrict__ deg,
    const int* __restrict__ ecol, const float* __restrict__ ew)
{
    const int wave = threadIdx.x >> 6, l = threadIdx.x & 63;
    const int row = blockIdx.x * 4 + wave;
    float acc[8];
    #pragma unroll
    for (int i = 0; i < 8; i++) acc[i] = 0.f;
    const int start = offs[row], d = deg[row];
    for (int j = 0; j < d; j++) {
        int col = ecol[start + j];
        float w = ew[start + j];
        const float4* xr = (const float4*)(X + (size_t)col * 512) + l * 2;
        float4 a = xr[0], b = xr[1];
        acc[0] = fmaf(w, a.x, acc[0]); acc[1] = fmaf(w, a.y, acc[1]);
        acc[2] = fmaf(w, a.z, acc[2]); acc[3] = fmaf(w, a.w, acc[3]);
        acc[4] = fmaf(w, b.x, acc[4]); acc[5] = fmaf(w, b.y, acc[5]);
        acc[6] = fmaf(w, b.z, acc[6]); acc[7] = fmaf(w, b.w, acc[7]);
    }
    uint4 o;
    o.x = packbf2(acc[0], acc[1]);
    o.y = packbf2(acc[2], acc[3]);
    o.z = packbf2(acc[4], acc[5]);
    o.w = packbf2(acc[6], acc[7]);
    ((uint4*)D)[(size_t)row * 64 + l] = o;
}

// ---- CSR gather (bf16 in/out, fp32 accum): D[row]=relu(bias + Σ w*S[col] + Σw*c[g]) ----
__global__ __launch_bounds__(256) void gather_kernel(
    const ushort16* __restrict__ S, ushort16* __restrict__ D,
    const int* __restrict__ offs, const int* __restrict__ deg,
    const int* __restrict__ ecol, const float* __restrict__ ew,
    const float* __restrict__ bias, const float* __restrict__ cadd, int nPerGraph)
{
    const int wave = threadIdx.x >> 6, l = threadIdx.x & 63;
    const int row = blockIdx.x * 4 + wave;
    const uint4* S4 = (const uint4*)S;     // 64 x uint4 per row
    float acc[8];
    {
        float4 b0 = ((const float4*)bias)[l * 2];
        float4 b1 = ((const float4*)bias)[l * 2 + 1];
        acc[0] = b0.x; acc[1] = b0.y; acc[2] = b0.z; acc[3] = b0.w;
        acc[4] = b1.x; acc[5] = b1.y; acc[6] = b1.z; acc[7] = b1.w;
    }
    const int start = offs[row], d = deg[row];
    float sw = 0.f;
    for (int j = 0; j < d; j++) {
        int col = ecol[start + j];
        float w = ew[start + j];
        uint4 s = S4[(size_t)col * 64 + l];
        acc[0] = fmaf(w, bf_lo(s.x), acc[0]); acc[1] = fmaf(w, bf_hi(s.x), acc[1]);
        acc[2] = fmaf(w, bf_lo(s.y), acc[2]); acc[3] = fmaf(w, bf_hi(s.y), acc[3]);
        acc[4] = fmaf(w, bf_lo(s.z), acc[4]); acc[5] = fmaf(w, bf_hi(s.z), acc[5]);
        acc[6] = fmaf(w, bf_lo(s.w), acc[6]); acc[7] = fmaf(w, bf_hi(s.w), acc[7]);
        sw += w;
    }
    {
        const float* c = cadd + (size_t)(row / nPerGraph) * 512 + l * 8;
        #pragma unroll
        for (int i = 0; i < 8; i++) acc[i] = fmaf(sw, c[i], acc[i]);
    }
    uint4 o;
    o.x = packbf2(fmaxf(acc[0], 0.f), fmaxf(acc[1], 0.f));
    o.y = packbf2(fmaxf(acc[2], 0.f), fmaxf(acc[3], 0.f));
    o.z = packbf2(fmaxf(acc[4], 0.f), fmaxf(acc[5], 0.f));
    o.w = packbf2(fmaxf(acc[6], 0.f), fmaxf(acc[7], 0.f));
    ((uint4*)D)[(size_t)row * 64 + l] = o;
}

// ---------------- bf16 MFMA GEMM: C[M,512] = A[M,512] @ Wt^T ----------------
// Counted-vmcnt pipeline, DEPTH 3 (2 tiles in flight at each barrier): 3 LDS buffers,
// steady-state s_waitcnt vmcnt(8) (stages kt+1, kt+2 in flight; 4 glds each; never 0
// mid-loop). Same barrier/read/write structure proven in r2/r4/r5; only buffer count
// and wait literals changed. Fully unrolled (K=512, 16 tiles) -> all indices static.
// Epilogues: CMODE 0: C bf16. CMODE 1: C fp32 += cadd[g], leaky. CMODE 2: C bf16 =
// relu(acc + bias[col]); root row saved pre-relu fp32 -> hroot.
template<int CMODE>
__global__ __launch_bounds__(256) void gemm_mfma_kernel(
    const ushort16* __restrict__ Ab, const ushort16* __restrict__ Bt,
    void* __restrict__ Cvoid, const float* __restrict__ cadd,
    const int* __restrict__ root_idx, float* __restrict__ hroot, int nPerGraph)
{
    __shared__ __align__(16) ushort16 As[3][128 * 32];
    __shared__ __align__(16) ushort16 Bs[3][128 * 32];

    const int t = threadIdx.x;
    const int id = blockIdx.x;
    const int bm = (id >> 5) * 8 + (id & 7);
    const int bn = (id >> 3) & 3;
    const int lane = t & 63, wave = t >> 6;
    const int wm = wave >> 1, wn = wave & 1;
    const int quad = lane >> 4, l16 = lane & 15;
    const int grow = lane >> 2;                         // row within 16-row segment
    const int gkc = (((lane & 3) ^ ((grow >> 1) & 3))) * 8;   // swizzled k-chunk (elems)
    const int swz = (l16 >> 1) & 3;                     // read-side chunk XOR

    const ushort16* Bbase = Bt + (size_t)(bn * 128) * 512;

    f32x4 acc[4][4];
    #pragma unroll
    for (int i = 0; i < 4; i++)
        #pragma unroll
        for (int j = 0; j < 4; j++)
            acc[i][j] = (f32x4){0.f, 0.f, 0.f, 0.f};

    // stage one 128x32 K-tile of A and B into buffer `buf` (4 gload_lds per lane)
    auto stage = [&](int k0, int buf) {
        #pragma unroll
        for (int j = 0; j < 2; j++) {
            int seg = wave * 2 + j;
            gload_lds16(Ab + (size_t)(bm * 128 + seg * 16 + grow) * 512 + k0 + gkc,
                        &As[buf][seg * 512 + lane * 8]);
            gload_lds16(Bbase + (size_t)(seg * 16 + grow) * 512 + k0 + gkc,
                        &Bs[buf][seg * 512 + lane * 8]);
        }
    };

    // prologue: 3 tiles in flight
    stage(0, 0);
    stage(32, 1);
    stage(64, 2);

    #pragma unroll
    for (int kt = 0; kt < 16; kt++) {
        const int buf = kt % 3;
        // wait for stage(kt); stages kt+1, kt+2 (4 glds each) may stay in flight
        if (kt <= 13)      { asm volatile("s_waitcnt vmcnt(8)" ::: "memory"); }
        else if (kt == 14) { asm volatile("s_waitcnt vmcnt(4)" ::: "memory"); }
        else               { asm volatile("s_waitcnt vmcnt(0)" ::: "memory"); }
        __builtin_amdgcn_sched_barrier(0);
        __builtin_amdgcn_s_barrier();          // all waves: stage(kt) landed
        __builtin_amdgcn_sched_barrier(0);

        short8 af[4], bfr[4];
        #pragma unroll
        for (int mi = 0; mi < 4; mi++)
            af[mi] = *(const short8*)
                &As[buf][(wm * 64 + mi * 16 + l16) * 32 + (quad ^ swz) * 8];
        #pragma unroll
        for (int ni = 0; ni < 4; ni++)
            bfr[ni] = *(const short8*)
                &Bs[buf][(wn * 64 + ni * 16 + l16) * 32 + (quad ^ swz) * 8];

        asm volatile("s_waitcnt lgkmcnt(0)" ::: "memory");
        __builtin_amdgcn_sched_barrier(0);
        __builtin_amdgcn_s_barrier();          // all waves done reading buf -> reusable
        __builtin_amdgcn_sched_barrier(0);

        if (kt + 3 < 16) stage((kt + 3) * 32, buf);   // refill freed buffer
        __builtin_amdgcn_sched_barrier(0);

        __builtin_amdgcn_s_setprio(1);
        #pragma unroll
        for (int mi = 0; mi < 4; mi++)
            #pragma unroll
            for (int ni = 0; ni < 4; ni++)
                acc[mi][ni] = __builtin_amdgcn_mfma_f32_16x16x32_bf16(
                    af[mi], bfr[ni], acc[mi][ni], 0, 0, 0);
        __builtin_amdgcn_s_setprio(0);
    }

    if (CMODE == 0) {
        ushort16* C2 = (ushort16*)Cvoid;
        #pragma unroll
        for (int ni = 0; ni < 4; ni++) {
            const int col = bn * 128 + wn * 64 + ni * 16 + l16;
            #pragma unroll
            for (int mi = 0; mi < 4; mi++) {
                const int row0 = bm * 128 + wm * 64 + mi * 16 + quad * 4;
                #pragma unroll
                for (int r = 0; r < 4; r++)
                    C2[(size_t)(row0 + r) * 512 + col] = f2bf(acc[mi][ni][r]);
            }
        }
    } else if (CMODE == 1) {
        float* Cf = (float*)Cvoid;
        const int g = (bm * 128) / nPerGraph;
        #pragma unroll
        for (int ni = 0; ni < 4; ni++) {
            const int col = bn * 128 + wn * 64 + ni * 16 + l16;
            const float cv = cadd[(size_t)g * 512 + col];
            #pragma unroll
            for (int mi = 0; mi < 4; mi++) {
                const int row0 = bm * 128 + wm * 64 + mi * 16 + quad * 4;
                #pragma unroll
                for (int r = 0; r < 4; r++) {
                    float v = acc[mi][ni][r] + cv;
                    v = v > 0.f ? v : 0.01f * v;
                    Cf[(size_t)(row0 + r) * 512 + col] = v;
                }
            }
        }
    } else {   // CMODE == 2: h1 epilogue — +bias, relu, root-row fp32 save
        ushort16* C2 = (ushort16*)Cvoid;
        const int g = (bm * 128) / nPerGraph;
        const int root = root_idx[g];
        #pragma unroll
        for (int ni = 0; ni < 4; ni++) {
            const int col = bn * 128 + wn * 64 + ni * 16 + l16;
            const float bv = cadd[col];
            #pragma unroll
            for (int mi = 0; mi < 4; mi++) {
                const int row0 = bm * 128 + wm * 64 + mi * 16 + quad * 4;
                #pragma unroll
                for (int r = 0; r < 4; r++) {
                    float v = acc[mi][ni][r] + bv;
                    if (row0 + r == root)
                        hroot[(size_t)g * 512 + col] = v;   // raw (pre-relu) fp32
                    C2[(size_t)(row0 + r) * 512 + col] = f2bf(fmaxf(v, 0.f));
                }
            }
        }
    }
}

// ---------------- per-graph root vectors (fp32, small) ----------------
__global__ __launch_bounds__(256) void rootvec_kernel(
    const float* __restrict__ X, const float* __restrict__ hroot,
    const int* __restrict__ root_idx,
    const float* __restrict__ W2full, const float* __restrict__ Wlfull,
    const float* __restrict__ bl,
    float* __restrict__ c2, float* __restrict__ c3)
{
    __shared__ float xs[512];
    __shared__ float red[4][64];
    const int g = blockIdx.x, which = blockIdx.y, chunk = blockIdx.z;
    const int t = threadIdx.x;
    const float* src = which ? (hroot + (size_t)g * 512)
                             : (X + (size_t)root_idx[g] * 512);
    const float* W = (which ? Wlfull : W2full) + 512 * 512;

    for (int k = t; k < 512; k += 256) {
        float v = src[k];
        if (which == 0) v = fmaxf(v, 0.f);
        xs[k] = v;
    }
    __syncthreads();

    const int col = chunk * 64 + (t & 63), kg = t >> 6;
    float acc = 0.f;
    #pragma unroll 4
    for (int k = kg * 128; k < kg * 128 + 128; k++)
        acc = fmaf(xs[k], W[(size_t)k * 512 + col], acc);
    red[kg][t & 63] = acc;
    __syncthreads();
    if (t < 64) {
        float s = red[0][t] + red[1][t] + red[2][t] + red[3][t];
        int c = chunk * 64 + t;
        if (which) c3[(size_t)g * 512 + c] = s + bl[c];
        else       c2[(size_t)g * 512 + c] = s;
    }
}

extern "C" void kernel_launch(void* const* d_in, const int* in_sizes, int n_in,
                              void* d_out, int out_size, void* d_ws, size_t ws_size,
                              hipStream_t stream)
{
    const float* X        = (const float*)d_in[0];
    const int*   adjs     = (const int*)d_in[1];
    const float* vals     = (const float*)d_in[2];
    const int*   root_idx = (const int*)d_in[3];
    const float* W1       = (const float*)d_in[6];
    const float* b1       = (const float*)d_in[7];
    const float* W2       = (const float*)d_in[8];
    const float* b2       = (const float*)d_in[9];
    const float* Wl       = (const float*)d_in[10];
    const float* bl       = (const float*)d_in[11];
    float* out = (float*)d_out;

    const int M    = in_sizes[0] / 512;   // 65536 nodes total
    const int Etot = in_sizes[2];         // 65536 edges total
    const int Bg   = in_sizes[3];         // 16 graphs
    const int N    = M / Bg;              // 4096 nodes/graph

    // workspace layout
    ushort16* bufS  = (ushort16*)d_ws;                     // aggX / s2 (bf16)
    ushort16* bufH  = bufS + (size_t)M * 512;              // relu(h1) / relu(agg2) (bf16)
    ushort16* Wt    = bufH + (size_t)M * 512;              // 3 x 512x512 bf16 [n][k]
    float*    c2    = (float*)(Wt + (size_t)3 * 512 * 512);
    float*    c3    = c2 + (size_t)Bg * 512;
    float*    hroot = c3 + (size_t)Bg * 512;               // raw fp32 h1 root rows
    int*      deg    = (int*)(hroot + (size_t)Bg * 512);
    int*      cursor = deg + M;
    int*      offs   = cursor + M;
    int*      bsum   = offs + M;
    int*      ecol   = bsum + 256;
    float*    ew     = (float*)(ecol + Etot);

    const int* rows = adjs;          // adjs[0] = src (segment target)
    const int* cols = adjs + Etot;   // adjs[1] = dst (gather source)

    const int eBlocks = (Etot + 255) / 256;
    dim3 gemmGrid((M / 128) * 4);    // 1-D, XCD-swizzled inside kernel

    // --- weights -> bf16 transposed ---
    convertW_kernel<<<dim3(16, 16, 3), 256, 0, stream>>>(W1, W2, Wl, Wt);

    // --- CSR build ---
    zero_kernel<<<(2 * M + 255) / 256, 256, 0, stream>>>(deg, 2 * M);   // deg + cursor
    hist_kernel<<<eBlocks, 256, 0, stream>>>(rows, deg, Etot);
    scan_block_kernel<<<M / 256, 256, 0, stream>>>(deg, offs, bsum);
    scan_top_kernel<<<1, 256, 0, stream>>>(bsum);
    scan_add_kernel<<<M / 256, 256, 0, stream>>>(offs, bsum);
    fill_kernel<<<eBlocks, 256, 0, stream>>>(rows, cols, vals, offs, cursor, ecol, ew, Etot);

    // --- 1a. aggX = gather(X) -> bufS (bf16). Linearity: Agg(X@W1) == (AggX)@W1 ---
    gatherX_kernel<<<M / 4, 256, 0, stream>>>(X, bufS, offs, deg, ecol, ew);
    // --- 1b. bufH = relu(b1 + aggX @ W1); hroot = raw fp32 root rows (pre-relu) ---
    gemm_mfma_kernel<2><<<gemmGrid, 256, 0, stream>>>(bufS, Wt, bufH, b1,
                                                      root_idx, hroot, N);
    // --- 2. root vectors: c2 (from X), c3 (from hroot) ---
    rootvec_kernel<<<dim3(Bg, 2, 8), 256, 0, stream>>>(X, hroot, root_idx, W2, Wl, bl, c2, c3);
    // --- 3. s2 = relu(h1) @ W2a -> bufS (counted-vmcnt pipeline) ---
    gemm_mfma_kernel<0><<<gemmGrid, 256, 0, stream>>>(bufH, Wt + (size_t)512 * 512, bufS,
                                                      (const float*)nullptr,
                                                      (const int*)nullptr, (float*)nullptr, N);
    // --- 4. bufH = relu(b2 + sw*c2[g] + gather(w * s2[col])) ---
    gather_kernel<<<M / 4, 256, 0, stream>>>(bufS, bufH, offs, deg, ecol, ew, b2, c2, N);
    // --- 5. out = leaky(relu(agg2) @ Wla + c3[g]) -> d_out (fp32) ---
    gemm_mfma_kernel<1><<<gemmGrid, 256, 0, stream>>>(bufH, Wt + (size_t)2 * 512 * 512,
                                                      out, c3,
                                                      (const int*)nullptr, (float*)nullptr, N);
}